// Round 4
// baseline (2909.102 us; speedup 1.0000x reference)
//
#include <hip/hip_runtime.h>
#include <hip/hip_bf16.h>
#include <math.h>

#define EPSF 1e-12f
#define H 256
#define TSTEPS 4096
#define BATCH 32
#define TB (TSTEPS*BATCH)
#define BH (BATCH*H)

typedef _Float16 h2 __attribute__((ext_vector_type(2)));

#if defined(__has_builtin)
#if __has_builtin(__builtin_amdgcn_fdot2)
#define FDOT2(a, b, c) __builtin_amdgcn_fdot2((a), (b), (c), false)
#endif
#endif
#ifndef FDOT2
#define FDOT2(a, b, c) fmaf((float)(a).y, (float)(b).y, fmaf((float)(a).x, (float)(b).x, (c)))
#endif

#define BC(u) __builtin_bit_cast(h2, (u))

// DPP cross-lane: result = src from permuted lane (VALU pipe, no LDS traffic)
#define DPPF(x, ctrl) __builtin_bit_cast(float, __builtin_amdgcn_update_dpp( \
    0, __builtin_bit_cast(int, (x)), (ctrl), 0xf, 0xf, true))
#define DPP_QUAD_XOR1 0xB1   // quad_perm [1,0,3,2]
#define DPP_QUAD_XOR2 0x4E   // quad_perm [2,3,0,1]
#define DPP_HALF_MIRROR 0x141
#define DPP_ROW_MIRROR  0x140

// barrier without vmcnt drain (lgkmcnt only)
__device__ __forceinline__ void bar_nodrain() {
  __builtin_amdgcn_sched_barrier(0);
  asm volatile("s_waitcnt lgkmcnt(0)" ::: "memory");
  __builtin_amdgcn_s_barrier();
  __builtin_amdgcn_sched_barrier(0);
}

// ---------------- block-wide sum over 256 threads (4 waves) ----------------
__device__ __forceinline__ float block_sum256(float v, float* red) {
  #pragma unroll
  for (int o = 32; o > 0; o >>= 1) v += __shfl_down(v, o, 64);
  __syncthreads();
  if ((threadIdx.x & 63) == 0) red[threadIdx.x >> 6] = v;
  __syncthreads();
  return red[0] + red[1] + red[2] + red[3];
}

// ---------------- kernel 1: spectral sigmas + normalized bias ----------------
// wsc[0..255] = b_sn, wsc[256] = 1/sigma_ih, wsc[257] = 1/sigma_hh
__global__ __launch_bounds__(256) void k_prep(
    const float* __restrict__ w_ih, const float* __restrict__ w_hh,
    const float* __restrict__ b_ih, const float* __restrict__ b_hh,
    const float* __restrict__ u_ih, const float* __restrict__ u_hh,
    float* __restrict__ wsc) {
  __shared__ float red[4];
  __shared__ float ubuf[H];
  __shared__ float vbuf[H];
  const int tid = threadIdx.x;

  float inv_sig[2];
  const float* Ws[2] = {w_ih, w_hh};
  const float* Us[2] = {u_ih, u_hh};
  #pragma unroll 1
  for (int m = 0; m < 2; m++) {
    const float* W = Ws[m];
    float uv = Us[m][tid];
    float nu = sqrtf(block_sum256(uv * uv, red));
    ubuf[tid] = uv / (nu + EPSF);
    __syncthreads();
    float vt = 0.f;
    for (int h = 0; h < H; h++) vt = fmaf(W[h * H + tid], ubuf[h], vt);
    float nv = sqrtf(block_sum256(vt * vt, red));
    vbuf[tid] = vt / (nv + EPSF);
    __syncthreads();
    float wv = 0.f;
    const float* wr = W + (size_t)tid * H;
    for (int i = 0; i < H; i++) wv = fmaf(wr[i], vbuf[i], wv);
    float n2 = block_sum256(wv * wv, red);
    float sigma = n2 / (sqrtf(n2) + EPSF);
    inv_sig[m] = 1.f / sigma;
  }
  float bi = b_ih[tid], bh = b_hh[tid];
  float nbi = sqrtf(block_sum256(bi * bi, red));
  float nbh = sqrtf(block_sum256(bh * bh, red));
  wsc[tid] = bi / (nbi + EPSF) + bh / (nbh + EPSF);
  if (tid == 0) { wsc[H] = inv_sig[0]; wsc[H + 1] = inv_sig[1]; }
}

// ---------------- kernel 1b: Wt16[k][h] = f16(w_ih[h][k] / sigma_ih) ---------
// R9: transposed, pre-scaled f16 copy of W_ih so k_pre's per-lane W loads are
// COALESCED (R8's 8KB-stride scatter was the regression). 64K elems, one-shot.
__global__ __launch_bounds__(256) void k_wcvt(
    const float* __restrict__ w_ih, const float* __restrict__ wsc,
    _Float16* __restrict__ wt) {
  const int h = blockIdx.x, k = threadIdx.x;
  wt[(size_t)k * H + h] = (_Float16)(w_ih[(size_t)h * H + k] * wsc[H]);
}

// ---------------- kernel 2: pre = x @ W_ih_sn^T + b_sn -> out[0:T*B*H] -------
// 8m x 8h register tile (R8) + coalesced f16 W-T loads (R9). x path f32 as
// before. f32 fmaf MACs; scale folded into Wt16; epilogue adds bias only.
__global__ __launch_bounds__(256) void k_pre(
    const float* __restrict__ x, const _Float16* __restrict__ wt,
    const float* __restrict__ wsc, float* __restrict__ pre) {
  __shared__ float xs[64 * 256];        // 64 KB x-tile
  const int tid = threadIdx.x;
  const size_t m0 = (size_t)blockIdx.x * 64;

  // stage 64 rows of x (coalesced float4): 16 per thread
  const float4* xp = (const float4*)(x + m0 * H);
  float4* xsv = (float4*)xs;
  #pragma unroll
  for (int j = 0; j < 16; j++) xsv[j * 256 + tid] = xp[j * 256 + tid];
  __syncthreads();

  const int hg = tid & 31;        // h group: columns 8*hg .. +7
  const int mg = tid >> 5;        // m group: rows 8*mg .. +7
  const int h0 = hg << 3;
  const int mr0 = mg << 3;

  float acc[8][8];
  #pragma unroll
  for (int i = 0; i < 8; i++)
    #pragma unroll
    for (int j = 0; j < 8; j++) acc[i][j] = 0.f;

  #pragma unroll 1
  for (int kb = 0; kb < 256; kb += 4) {
    float wf[4][8];
    #pragma unroll
    for (int j = 0; j < 4; j++) {
      // lanes hg=0..31 read contiguous 16B: coalesced 512B/wave-instr
      uint4 wv = *(const uint4*)(wt + (size_t)(kb + j) * H + h0);
      h2 p0 = BC(wv.x), p1 = BC(wv.y), p2 = BC(wv.z), p3 = BC(wv.w);
      wf[j][0] = (float)p0.x; wf[j][1] = (float)p0.y;
      wf[j][2] = (float)p1.x; wf[j][3] = (float)p1.y;
      wf[j][4] = (float)p2.x; wf[j][5] = (float)p2.y;
      wf[j][6] = (float)p3.x; wf[j][7] = (float)p3.y;
    }
    #pragma unroll
    for (int i = 0; i < 8; i++) {
      float4 xv = *(const float4*)(xs + (mr0 + i) * 256 + kb);  // 2-addr broadcast
      #pragma unroll
      for (int j = 0; j < 8; j++) {
        float a = acc[i][j];
        a = fmaf(xv.x, wf[0][j], a);
        a = fmaf(xv.y, wf[1][j], a);
        a = fmaf(xv.z, wf[2][j], a);
        a = fmaf(xv.w, wf[3][j], a);
        acc[i][j] = a;
      }
    }
  }
  float bs[8];
  #pragma unroll
  for (int j = 0; j < 8; j++) bs[j] = wsc[h0 + j];
  #pragma unroll
  for (int i = 0; i < 8; i++) {
    float4 o0, o1;
    o0.x = acc[i][0] + bs[0];
    o0.y = acc[i][1] + bs[1];
    o0.z = acc[i][2] + bs[2];
    o0.w = acc[i][3] + bs[3];
    o1.x = acc[i][4] + bs[4];
    o1.y = acc[i][5] + bs[5];
    o1.z = acc[i][6] + bs[6];
    o1.w = acc[i][7] + bs[7];
    float* pr = pre + (m0 + mr0 + i) * H + h0;
    *(float4*)pr = o0;
    *(float4*)(pr + 4) = o1;
  }
}

// swizzle a byte offset within a 512B hbuf
__device__ __forceinline__ int swz(int a) { return a ^ (((a >> 8) & 1) << 6); }

// ---------------- kernel 3: sequential scan, one block per batch element ----
// R9: active-CU VALUBusy ~77% => issue-bound; back-fit says v_dot2_f32_f16 is
// ~4-8cy (not full rate). Replace with v_pk_fma_f16 (full rate 2cy): 8 pk_fma
// into a packed f16 pair per row, one FDOT2x{1,1} finalize to f32. Each f16
// half-acc sums only 8 products (rms err ~2e-4, safe). Rest unchanged.
__global__ __launch_bounds__(512, 1) void k_scan(
    const float* __restrict__ state, const float* __restrict__ w_hh,
    const float* __restrict__ wsc, float* __restrict__ out) {
  __shared__ __align__(16) _Float16 hbuf[2][H];   // 512 B each, 64B-swizzled
  const int tid = threadIdx.x;
  const int cg   = tid >> 6;      // wave id: rows [32cg, 32cg+32)
  const int q    = tid & 63;
  const int rgrp = q >> 4;        // row octet: rows 32cg+8rgrp+[0,8)
  const int kseg = q & 15;        // k in [16kseg, 16kseg+16)
  const int jrow = 4 * ((q >> 3) & 1) + 2 * ((q >> 2) & 1) + ((q >> 1) & 1);
  const int myrow = (cg << 5) + (rgrp << 3) + jrow;
  const int b = blockIdx.x;
  const float inv_s = wsc[H + 1];
  const bool hb3 = (q >> 3) & 1, hb2 = (q >> 2) & 1, hb1 = (q >> 1) & 1;
  const h2 one2 = h2{(_Float16)1.f, (_Float16)1.f};

  h2 wreg[8][8];
  #pragma unroll
  for (int i = 0; i < 8; i++) {
    const float* wr = w_hh + (size_t)((cg << 5) + (rgrp << 3) + i) * H + (kseg << 4);
    #pragma unroll
    for (int c = 0; c < 8; c++) {
      float2 wv = *(const float2*)(wr + 2 * c);
      wreg[i][c] = h2{(_Float16)(wv.x * inv_s), (_Float16)(wv.y * inv_s)};
    }
  }

  const int a0s = swz(kseg << 5);
  const int a1s = swz((kseg << 5) + 16);
  const int woff = swz(myrow * 2);

  if (tid < H)
    *(_Float16*)((char*)&hbuf[0][0] + swz(tid * 2)) = (_Float16)state[b * H + tid];

  const float* pbase = out + (size_t)b * H + myrow;
  float pre0 = pbase[0], pre1 = pbase[BH];
  bar_nodrain();

  float hn = 0.f;
  #pragma unroll 1
  for (int t = 0; t < TSTEPS; t++) {
    int tn = (t + 2 <= TSTEPS) ? (t + 2) : TSTEPS;   // clamp into h_last region
    float pre2 = pbase[(size_t)tn * BH];

    const char* hb = (const char*)&hbuf[t & 1][0];
    uint4 q0 = *(const uint4*)(hb + a0s);
    uint4 q1 = *(const uint4*)(hb + a1s);

    float acc[8];
    #pragma unroll
    for (int i = 0; i < 8; i++) {
      h2 a2 = wreg[i][0] * BC(q0.x);           // v_pk_mul_f16
      a2 = wreg[i][1] * BC(q0.y) + a2;         // v_pk_fma_f16 x7
      a2 = wreg[i][2] * BC(q0.z) + a2;
      a2 = wreg[i][3] * BC(q0.w) + a2;
      a2 = wreg[i][4] * BC(q1.x) + a2;
      a2 = wreg[i][5] * BC(q1.y) + a2;
      a2 = wreg[i][6] * BC(q1.z) + a2;
      a2 = wreg[i][7] * BC(q1.w) + a2;
      acc[i] = FDOT2(a2, one2, 0.f);           // (lo + hi) in f32
    }

    // reduce-scatter over 16 ksegs (one DPP row), all-VALU.
    float v0, v1, v2, v3;
    { float k0 = hb3 ? acc[4] : acc[0], s0 = hb3 ? acc[0] : acc[4];
      float k1 = hb3 ? acc[5] : acc[1], s1 = hb3 ? acc[1] : acc[5];
      float k2 = hb3 ? acc[6] : acc[2], s2 = hb3 ? acc[2] : acc[6];
      float k3 = hb3 ? acc[7] : acc[3], s3 = hb3 ? acc[3] : acc[7];
      v0 = k0 + DPPF(s0, DPP_ROW_MIRROR);
      v1 = k1 + DPPF(s1, DPP_ROW_MIRROR);
      v2 = k2 + DPPF(s2, DPP_ROW_MIRROR);
      v3 = k3 + DPPF(s3, DPP_ROW_MIRROR); }
    float u0, u1;
    { float k0 = hb2 ? v2 : v0, s0 = hb2 ? v0 : v2;
      float k1 = hb2 ? v3 : v1, s1 = hb2 ? v1 : v3;
      u0 = k0 + DPPF(s0, DPP_HALF_MIRROR);
      u1 = k1 + DPPF(s1, DPP_HALF_MIRROR); }
    float ssum;
    { float k0 = hb1 ? u1 : u0, s0 = hb1 ? u0 : u1;
      ssum = k0 + DPPF(s0, DPP_QUAD_XOR2); }
    ssum += DPPF(ssum, DPP_QUAD_XOR1);

    float s = ssum + pre0;
    float sc = fminf(fmaxf(s, -15.f), 15.f);
    float e = __expf(2.f * sc);
    hn = __fdividef(e - 1.f, e + 1.f);   // tanh

    if (!(q & 1)) {                      // even lane of each pair publishes
      *(_Float16*)((char*)&hbuf[(t + 1) & 1][0] + woff) = (_Float16)hn;
      out[(size_t)t * BH + b * H + myrow] = hn;   // overwrite pre slot (f32)
    }
    bar_nodrain();                       // single barrier per step
    pre0 = pre1; pre1 = pre2;
  }
  if (!(q & 1)) out[(size_t)TSTEPS * BH + b * H + myrow] = hn;   // h_last
}

// ---------------- launcher ---------------------------------------------------
extern "C" void kernel_launch(void* const* d_in, const int* in_sizes, int n_in,
                              void* d_out, int out_size, void* d_ws, size_t ws_size,
                              hipStream_t stream) {
  const float* x     = (const float*)d_in[0];
  const float* state = (const float*)d_in[1];
  const float* w_ih  = (const float*)d_in[2];
  const float* w_hh  = (const float*)d_in[3];
  const float* b_ih  = (const float*)d_in[4];
  const float* b_hh  = (const float*)d_in[5];
  const float* u_ih  = (const float*)d_in[6];
  const float* u_hh  = (const float*)d_in[7];
  float* out = (float*)d_out;
  float* wsc = (float*)d_ws;                      // 258 floats of scratch
  _Float16* wt = (_Float16*)((char*)d_ws + 2048); // 128 KB transposed f16 W_ih

  k_prep<<<1, 256, 0, stream>>>(w_ih, w_hh, b_ih, b_hh, u_ih, u_hh, wsc);
  k_wcvt<<<H, 256, 0, stream>>>(w_ih, wsc, wt);
  k_pre<<<TB / 64, 256, 0, stream>>>(x, wt, wsc, out);
  k_scan<<<BATCH, 512, 0, stream>>>(state, w_hh, wsc, out);
}

// Round 6
// 2721.266 us; speedup vs baseline: 1.0690x; 1.0690x over previous
//
#include <hip/hip_runtime.h>
#include <hip/hip_bf16.h>
#include <math.h>

#define EPSF 1e-12f
#define H 256
#define TSTEPS 4096
#define BATCH 32
#define TB (TSTEPS*BATCH)
#define BH (BATCH*H)

typedef _Float16 h2 __attribute__((ext_vector_type(2)));

#define BC(u) __builtin_bit_cast(h2, (u))

// DPP cross-lane: result = src from permuted lane (VALU pipe, no LDS traffic)
#define DPPF(x, ctrl) __builtin_bit_cast(float, __builtin_amdgcn_update_dpp( \
    0, __builtin_bit_cast(int, (x)), (ctrl), 0xf, 0xf, true))
#define DPP_QUAD_XOR1 0xB1   // quad_perm [1,0,3,2]
#define DPP_QUAD_XOR2 0x4E   // quad_perm [2,3,0,1]
#define DPP_HALF_MIRROR 0x141
#define DPP_ROW_MIRROR  0x140

// barrier without vmcnt drain (lgkmcnt only)
__device__ __forceinline__ void bar_nodrain() {
  __builtin_amdgcn_sched_barrier(0);
  asm volatile("s_waitcnt lgkmcnt(0)" ::: "memory");
  __builtin_amdgcn_s_barrier();
  __builtin_amdgcn_sched_barrier(0);
}

// ---------------- block-wide sum over 256 threads (4 waves) ----------------
__device__ __forceinline__ float block_sum256(float v, float* red) {
  #pragma unroll
  for (int o = 32; o > 0; o >>= 1) v += __shfl_down(v, o, 64);
  __syncthreads();
  if ((threadIdx.x & 63) == 0) red[threadIdx.x >> 6] = v;
  __syncthreads();
  return red[0] + red[1] + red[2] + red[3];
}

// ---------------- kernel 1: spectral sigmas + normalized bias ----------------
// wsc[0..255] = b_sn, wsc[256] = 1/sigma_ih, wsc[257] = 1/sigma_hh
__global__ __launch_bounds__(256) void k_prep(
    const float* __restrict__ w_ih, const float* __restrict__ w_hh,
    const float* __restrict__ b_ih, const float* __restrict__ b_hh,
    const float* __restrict__ u_ih, const float* __restrict__ u_hh,
    float* __restrict__ wsc) {
  __shared__ float red[4];
  __shared__ float ubuf[H];
  __shared__ float vbuf[H];
  const int tid = threadIdx.x;

  float inv_sig[2];
  const float* Ws[2] = {w_ih, w_hh};
  const float* Us[2] = {u_ih, u_hh};
  #pragma unroll 1
  for (int m = 0; m < 2; m++) {
    const float* W = Ws[m];
    float uv = Us[m][tid];
    float nu = sqrtf(block_sum256(uv * uv, red));
    ubuf[tid] = uv / (nu + EPSF);
    __syncthreads();
    float vt = 0.f;
    for (int h = 0; h < H; h++) vt = fmaf(W[h * H + tid], ubuf[h], vt);
    float nv = sqrtf(block_sum256(vt * vt, red));
    vbuf[tid] = vt / (nv + EPSF);
    __syncthreads();
    float wv = 0.f;
    const float* wr = W + (size_t)tid * H;
    for (int i = 0; i < H; i++) wv = fmaf(wr[i], vbuf[i], wv);
    float n2 = block_sum256(wv * wv, red);
    float sigma = n2 / (sqrtf(n2) + EPSF);
    inv_sig[m] = 1.f / sigma;
  }
  float bi = b_ih[tid], bh = b_hh[tid];
  float nbi = sqrtf(block_sum256(bi * bi, red));
  float nbh = sqrtf(block_sum256(bh * bh, red));
  wsc[tid] = bi / (nbi + EPSF) + bh / (nbh + EPSF);
  if (tid == 0) { wsc[H] = inv_sig[0]; wsc[H + 1] = inv_sig[1]; }
}

// ---------------- kernel 1b: Wt16[k][h] = f16(w_ih[h][k] / sigma_ih) ---------
// transposed, pre-scaled f16 copy of W_ih so k_pre's per-lane W loads are
// coalesced (fixed R8's 8KB-stride scatter). 64K elems, one-shot.
__global__ __launch_bounds__(256) void k_wcvt(
    const float* __restrict__ w_ih, const float* __restrict__ wsc,
    _Float16* __restrict__ wt) {
  const int h = blockIdx.x, k = threadIdx.x;
  wt[(size_t)k * H + h] = (_Float16)(w_ih[(size_t)h * H + k] * wsc[H]);
}

// ---------------- kernel 2: pre = x @ W_ih_sn^T + b_sn -> out[0:T*B*H] -------
// 8m x 8h register tile + coalesced f16 W-T loads. f32 fmaf MACs.
__global__ __launch_bounds__(256) void k_pre(
    const float* __restrict__ x, const _Float16* __restrict__ wt,
    const float* __restrict__ wsc, float* __restrict__ pre) {
  __shared__ float xs[64 * 256];        // 64 KB x-tile
  const int tid = threadIdx.x;
  const size_t m0 = (size_t)blockIdx.x * 64;

  const float4* xp = (const float4*)(x + m0 * H);
  float4* xsv = (float4*)xs;
  #pragma unroll
  for (int j = 0; j < 16; j++) xsv[j * 256 + tid] = xp[j * 256 + tid];
  __syncthreads();

  const int hg = tid & 31;        // h group: columns 8*hg .. +7
  const int mg = tid >> 5;        // m group: rows 8*mg .. +7
  const int h0 = hg << 3;
  const int mr0 = mg << 3;

  float acc[8][8];
  #pragma unroll
  for (int i = 0; i < 8; i++)
    #pragma unroll
    for (int j = 0; j < 8; j++) acc[i][j] = 0.f;

  #pragma unroll 1
  for (int kb = 0; kb < 256; kb += 4) {
    float wf[4][8];
    #pragma unroll
    for (int j = 0; j < 4; j++) {
      // lanes hg=0..31 read contiguous 16B: coalesced 512B/wave-instr
      uint4 wv = *(const uint4*)(wt + (size_t)(kb + j) * H + h0);
      h2 p0 = BC(wv.x), p1 = BC(wv.y), p2 = BC(wv.z), p3 = BC(wv.w);
      wf[j][0] = (float)p0.x; wf[j][1] = (float)p0.y;
      wf[j][2] = (float)p1.x; wf[j][3] = (float)p1.y;
      wf[j][4] = (float)p2.x; wf[j][5] = (float)p2.y;
      wf[j][6] = (float)p3.x; wf[j][7] = (float)p3.y;
    }
    #pragma unroll
    for (int i = 0; i < 8; i++) {
      float4 xv = *(const float4*)(xs + (mr0 + i) * 256 + kb);  // 2-addr broadcast
      #pragma unroll
      for (int j = 0; j < 8; j++) {
        float a = acc[i][j];
        a = fmaf(xv.x, wf[0][j], a);
        a = fmaf(xv.y, wf[1][j], a);
        a = fmaf(xv.z, wf[2][j], a);
        a = fmaf(xv.w, wf[3][j], a);
        acc[i][j] = a;
      }
    }
  }
  float bs[8];
  #pragma unroll
  for (int j = 0; j < 8; j++) bs[j] = wsc[h0 + j];
  #pragma unroll
  for (int i = 0; i < 8; i++) {
    float4 o0, o1;
    o0.x = acc[i][0] + bs[0];
    o0.y = acc[i][1] + bs[1];
    o0.z = acc[i][2] + bs[2];
    o0.w = acc[i][3] + bs[3];
    o1.x = acc[i][4] + bs[4];
    o1.y = acc[i][5] + bs[5];
    o1.z = acc[i][6] + bs[6];
    o1.w = acc[i][7] + bs[7];
    float* pr = pre + (m0 + mr0 + i) * H + h0;
    *(float4*)pr = o0;
    *(float4*)(pr + 4) = o1;
  }
}

// ---------------- kernel 3: sequential scan, one block per batch element ----
// R10: VALU-issue-bound confirmed (R4 regression tracked issue count 1:1).
// FDOT2 and v_pk_fma_f16 both measured ~6cy/wave64 (~3cy/MAC); plain
// v_fma_f32 is 2cy/MAC. Go all-f32: wreg f32[8][16] (128 VGPR, 2 waves/SIMD
// under (512,1)), h in f32 LDS. Swizzle idx = k + (k>>4)*4 (16B pad per 64B)
// makes the 16-kseg b128 reads and the publish writes 2-way = free.
// Issue model: 928 -> ~672 cy/step. Scan is now numerically near-exact.
__global__ __launch_bounds__(512, 1) void k_scan(
    const float* __restrict__ state, const float* __restrict__ w_hh,
    const float* __restrict__ wsc, float* __restrict__ out) {
  __shared__ __align__(16) float hbuf[2][320];    // 256 f32 + 4-f32 pad/16
  const int tid = threadIdx.x;
  const int cg   = tid >> 6;      // wave id: rows [32cg, 32cg+32)
  const int q    = tid & 63;
  const int rgrp = q >> 4;        // row octet: rows 32cg+8rgrp+[0,8)
  const int kseg = q & 15;        // k in [16kseg, 16kseg+16)
  const int jrow = 4 * ((q >> 3) & 1) + 2 * ((q >> 2) & 1) + ((q >> 1) & 1);
  const int myrow = (cg << 5) + (rgrp << 3) + jrow;
  const int b = blockIdx.x;
  const float inv_s = wsc[H + 1];
  const bool hb3 = (q >> 3) & 1, hb2 = (q >> 2) & 1, hb1 = (q >> 1) & 1;

  // stage W[32cg+8rgrp+i][16kseg..+16) as f32, pre-scaled: 128 VGPRs.
  // coalesced: for fixed i, lanes (rgrp,kseg=0..15) cover a full 1KB row.
  float wreg[8][16];
  #pragma unroll
  for (int i = 0; i < 8; i++) {
    const float* wr = w_hh + (size_t)((cg << 5) + (rgrp << 3) + i) * H + (kseg << 4);
    #pragma unroll
    for (int c4 = 0; c4 < 4; c4++) {
      float4 wv = *(const float4*)(wr + (c4 << 2));
      wreg[i][c4 * 4 + 0] = wv.x * inv_s;
      wreg[i][c4 * 4 + 1] = wv.y * inv_s;
      wreg[i][c4 * 4 + 2] = wv.z * inv_s;
      wreg[i][c4 * 4 + 3] = wv.w * inv_s;
    }
  }

  const int rbase = kseg * 20;                       // swizzled read base (f32 idx)
  const int wpub  = myrow + ((myrow >> 4) << 2);     // swizzled publish idx

  if (tid < H) hbuf[0][tid + ((tid >> 4) << 2)] = state[b * H + tid];

  const float* pbase = out + (size_t)b * H + myrow;
  float pre0 = pbase[0], pre1 = pbase[BH];
  bar_nodrain();

  float hn = 0.f;
  #pragma unroll 1
  for (int t = 0; t < TSTEPS; t++) {
    int tn = (t + 2 <= TSTEPS) ? (t + 2) : TSTEPS;   // clamp into h_last region
    float pre2 = pbase[(size_t)tn * BH];

    const float* hb = hbuf[t & 1];
    float4 r0 = *(const float4*)(hb + rbase);
    float4 r1 = *(const float4*)(hb + rbase + 4);
    float4 r2 = *(const float4*)(hb + rbase + 8);
    float4 r3 = *(const float4*)(hb + rbase + 12);
    float hk[16] = {r0.x, r0.y, r0.z, r0.w, r1.x, r1.y, r1.z, r1.w,
                    r2.x, r2.y, r2.z, r2.w, r3.x, r3.y, r3.z, r3.w};

    float acc[8];
    #pragma unroll
    for (int i = 0; i < 8; i++) {
      float a = 0.f;
      #pragma unroll
      for (int c = 0; c < 16; c++) a = fmaf(wreg[i][c], hk[c], a);
      acc[i] = a;
    }

    // reduce-scatter over 16 ksegs (one DPP row), all-VALU.
    float v0, v1, v2, v3;
    { float k0 = hb3 ? acc[4] : acc[0], s0 = hb3 ? acc[0] : acc[4];
      float k1 = hb3 ? acc[5] : acc[1], s1 = hb3 ? acc[1] : acc[5];
      float k2 = hb3 ? acc[6] : acc[2], s2 = hb3 ? acc[2] : acc[6];
      float k3 = hb3 ? acc[7] : acc[3], s3 = hb3 ? acc[3] : acc[7];
      v0 = k0 + DPPF(s0, DPP_ROW_MIRROR);
      v1 = k1 + DPPF(s1, DPP_ROW_MIRROR);
      v2 = k2 + DPPF(s2, DPP_ROW_MIRROR);
      v3 = k3 + DPPF(s3, DPP_ROW_MIRROR); }
    float u0, u1;
    { float k0 = hb2 ? v2 : v0, s0 = hb2 ? v0 : v2;
      float k1 = hb2 ? v3 : v1, s1 = hb2 ? v1 : v3;
      u0 = k0 + DPPF(s0, DPP_HALF_MIRROR);
      u1 = k1 + DPPF(s1, DPP_HALF_MIRROR); }
    float ssum;
    { float k0 = hb1 ? u1 : u0, s0 = hb1 ? u0 : u1;
      ssum = k0 + DPPF(s0, DPP_QUAD_XOR2); }
    ssum += DPPF(ssum, DPP_QUAD_XOR1);

    float s = ssum + pre0;
    float sc = fminf(fmaxf(s, -15.f), 15.f);
    float e = __expf(2.f * sc);
    hn = __fdividef(e - 1.f, e + 1.f);   // tanh

    if (!(q & 1)) {                      // even lane of each pair publishes
      hbuf[(t + 1) & 1][wpub] = hn;
      out[(size_t)t * BH + b * H + myrow] = hn;   // overwrite pre slot (f32)
    }
    bar_nodrain();                       // single barrier per step
    pre0 = pre1; pre1 = pre2;
  }
  if (!(q & 1)) out[(size_t)TSTEPS * BH + b * H + myrow] = hn;   // h_last
}

// ---------------- launcher ---------------------------------------------------
extern "C" void kernel_launch(void* const* d_in, const int* in_sizes, int n_in,
                              void* d_out, int out_size, void* d_ws, size_t ws_size,
                              hipStream_t stream) {
  const float* x     = (const float*)d_in[0];
  const float* state = (const float*)d_in[1];
  const float* w_ih  = (const float*)d_in[2];
  const float* w_hh  = (const float*)d_in[3];
  const float* b_ih  = (const float*)d_in[4];
  const float* b_hh  = (const float*)d_in[5];
  const float* u_ih  = (const float*)d_in[6];
  const float* u_hh  = (const float*)d_in[7];
  float* out = (float*)d_out;
  float* wsc = (float*)d_ws;                      // 258 floats of scratch
  _Float16* wt = (_Float16*)((char*)d_ws + 2048); // 128 KB transposed f16 W_ih

  k_prep<<<1, 256, 0, stream>>>(w_ih, w_hh, b_ih, b_hh, u_ih, u_hh, wsc);
  k_wcvt<<<H, 256, 0, stream>>>(w_ih, wsc, wt);
  k_pre<<<TB / 64, 256, 0, stream>>>(x, wt, wsc, out);
  k_scan<<<BATCH, 512, 0, stream>>>(state, w_hh, wsc, out);
}